// Round 4
// baseline (10478.734 us; speedup 1.0000x reference)
//
#include <hip/hip_runtime.h>
#include <hip/hip_bf16.h>
#include <hip/hip_fp16.h>

// Persistent dataflow RNN for MI355X (gfx950).
//   SEQ=4096, HID=2048, 4 layers. Grid 256 (R6 layout: layer = blockIdx&3).
//
// R10: self-contained waves — overlap the h-poll with x-MFMA.
// R9 post-mortem: one-XCD-per-layer needed 2 blocks/CU with a 128-VGPR
// afrag = 4 waves/SIMD x 128 = the ENTIRE 512-reg/SIMD file, zero margin;
// any VGPR creep -> half the layer non-resident -> bounded-spin livelock ->
// harness timeout. Also capacity-infeasible in principle (16MB weights/layer
// ~= one XCD's whole VGPR file). Branch abandoned; back to grid 256, 1
// block/CU guaranteed resident, single IC ring, no fast-ring, no barriers
// beyond one per step.
// R6's chain was: stage(all) -> BARRIER -> MFMA -> BARRIER -> reduce ->
// publish. Barrier #1 serialized the x-work behind the h-poll. Now each
// wave polls+stages only its OWN 1024-k slice (lane = 32B = 2 quads, one
// vmcnt window), ds_writes a private 2KB LDS slice, lgkmcnt-waits on
// itself, MFMAs immediately. x-waves (kq 0,1: ring[l-1] polls hit
// first-try in steady state) run stage+MFMA fully under the h-waves'
// (kq 2,3) poll. One barrier/step before the cross-wave k-reduce;
// partials double-buffered by t&1 (reduce(t) races next step's writers
// otherwise). Polls spin tight: sleep only after 6 misses (R6 slept every
// miss = +64-128cy per serial poll round). rb-twins duplicate slice polls
// (2x IC reads; R8 showed hot-line contention is not dominant).
// Carried from R6: tag-in-data single-trip protocol (parity in each u32's
// low fp16 LSB, prep re-tags anti-parity each launch), 512 thr / 8 waves,
// __launch_bounds__(512,2), 128 VGPRs/lane pinned fp16 weight fragments,
// relaxed agent publication, publish-before-out, bounded spins everywhere.

#define SEQ 4096
#define HID 2048
#define NL 4
#define WGS_PER_LAYER 64
#define ROWS_PER_WG 32
#define NT 32          // MFMA k-tiles per wave (k=1024 per wave)

typedef _Float16 f16x8 __attribute__((ext_vector_type(8)));
typedef float f32x4 __attribute__((ext_vector_type(4)));
typedef unsigned int u32x4 __attribute__((ext_vector_type(4)));
typedef unsigned long long u64;

__device__ __align__(16) _Float16 g_xin[(size_t)SEQ * HID];      // 16 MB
__device__ __align__(16) u64 g_ring[NL][SEQ][HID / 4];           // 67 MB (fp16 packed + tag LSBs)

// 8192 x 1024 = 8,388,608 = SEQ*HID = NL*SEQ*(HID/4) u64 — one grid does both.
__global__ void prep_kernel(const float* __restrict__ x) {
  size_t i = (size_t)blockIdx.x * blockDim.x + threadIdx.x;
  if (i < (size_t)SEQ * HID) g_xin[i] = (_Float16)x[i];
  if (i < (size_t)NL * SEQ * (HID / 4)) {
    size_t t = (i >> 9) & (SEQ - 1);                 // 512 u64 per (l,t) region
    unsigned int pat = (unsigned int)((t & 1) ^ 1);  // anti-parity tag
    u64 p64 = (u64)pat | ((u64)pat << 32);
    __hip_atomic_store(((u64*)g_ring) + i, p64, __ATOMIC_RELAXED,
                       __HIP_MEMORY_SCOPE_AGENT);    // visible at IC scope
  }
}

// 32B (2 quads) in one vmcnt window, bypass L1+L2 -> IC truth.
__device__ __forceinline__ void ld32_far(const void* p, u32x4& a, u32x4& b) {
  asm volatile(
      "global_load_dwordx4 %0, %2, off sc0 sc1\n\t"
      "global_load_dwordx4 %1, %2, off offset:16 sc0 sc1\n\t"
      "s_waitcnt vmcnt(0)"
      : "=&v"(a), "=&v"(b) : "v"(p) : "memory");
}
__device__ __forceinline__ bool tags_ok2(u32x4 a, u32x4 b, unsigned int exp) {
  unsigned int x = (a.x ^ exp) | (a.y ^ exp) | (a.z ^ exp) | (a.w ^ exp) |
                   (b.x ^ exp) | (b.y ^ exp) | (b.z ^ exp) | (b.w ^ exp);
  return (x & 1u) == 0u;
}

__global__ __launch_bounds__(512, 2) void rnn_kernel(
    const float* __restrict__ wih, const float* __restrict__ whh,
    float* __restrict__ out) {
  const int layer = blockIdx.x & 3;
  const int wg    = blockIdx.x >> 2;  // 0..63 within layer
  const int tid   = threadIdx.x;
  const int lane  = tid & 63;
  const int wave  = tid >> 6;         // 8 waves
  const int rb    = wave >> 2;        // row block: 0 -> rows 0..15, 1 -> 16..31
  const int kq    = wave & 3;         // k-range 0..3 (1024 k each); 0,1=x 2,3=h
  const int m     = lane & 15;
  const int q     = lane >> 4;
  const int row   = wg * ROWS_PER_WG + rb * 16 + m;

  // Per-wave private 2KB k-slice (no cross-wave staging dependency).
  __shared__ __align__(16) _Float16 catw[8][1024];
  // Double-buffered by t&1: reduce(t) races the next step's partial writes.
  __shared__ __align__(16) float partials[2][8][16];

  // ---- one-time: weights -> registers as fp16 A-fragments (128 VGPRs) ----
  // A layout (16x16x32): lane holds A[m][ktile + q*8 + j], j=0..7
  f32x4 afrag[NT];
  {
    const float* wl = wih + (size_t)layer * HID * HID + (size_t)row * HID;
    const float* wr = whh + (size_t)layer * HID * HID + (size_t)row * HID - HID;
#pragma unroll
    for (int i = 0; i < NT; ++i) {
      int kabs = kq * 1024 + i * 32 + q * 8;   // 1024-aligned ranges: never straddle 2048
      const float* src = (kabs < HID) ? (wl + kabs) : (wr + kabs);
      f32x4 w0 = *(const f32x4*)(src);
      f32x4 w1 = *(const f32x4*)(src + 4);
      f16x8 a;
      a[0] = (_Float16)w0[0]; a[1] = (_Float16)w0[1];
      a[2] = (_Float16)w0[2]; a[3] = (_Float16)w0[3];
      a[4] = (_Float16)w1[0]; a[5] = (_Float16)w1[1];
      a[6] = (_Float16)w1[2]; a[7] = (_Float16)w1[3];
      afrag[i] = __builtin_bit_cast(f32x4, a);
    }
#pragma unroll
    for (int i = 0; i < NT; ++i) asm volatile("" : "+v"(afrag[i]));  // pin
  }

  for (int t = 0; t < SEQ; ++t) {
    // ---- stage OWN 1024-k slice: lane loads 32B, polls until fresh ----
    {
      u32x4 va = {0u, 0u, 0u, 0u}, vb = {0u, 0u, 0u, 0u};
      if (kq < 2) {
        // x-slice [kq*1024, kq*1024+1024)
        if (layer == 0) {
          const u32x4* src =
              (const u32x4*)(g_xin + (size_t)t * HID + kq * 1024) + 2 * lane;
          va = src[0];
          vb = src[1];
        } else {
          const void* src =
              (const u64*)&g_ring[layer - 1][t][0] + (kq * 256 + lane * 4);
          const unsigned int exp = (unsigned int)(t & 1);
          int it = 0;
          for (;;) {   // steady state: first try hits (published a period ago)
            ld32_far(src, va, vb);
            if (tags_ok2(va, vb, exp)) break;
            if (++it > (1 << 20)) break;  // never hang the harness
            if (it > 6) __builtin_amdgcn_s_sleep(1);
          }
        }
      } else if (t > 0) {
        // h-slice [(kq-2)*1024, ...) of h_{t-1}: the serial recurrence poll.
        const void* src =
            (const u64*)&g_ring[layer][t - 1][0] + ((kq - 2) * 256 + lane * 4);
        const unsigned int exp = (unsigned int)((t - 1) & 1);
        int it = 0;
        for (;;) {
          ld32_far(src, va, vb);
          if (tags_ok2(va, vb, exp)) break;
          if (++it > (1 << 20)) break;
          if (it > 6) __builtin_amdgcn_s_sleep(1);
        }
      }
      // private slice write; only THIS wave reads it back.
      u32x4* slice = (u32x4*)&catw[wave][0];
      slice[2 * lane]     = va;
      slice[2 * lane + 1] = vb;
      asm volatile("s_waitcnt lgkmcnt(0)" ::: "memory");
      __builtin_amdgcn_sched_barrier(0);   // rule #18: don't hoist reads above
    }

    // ---- MFMA immediately (no block barrier): 16 rows x own 1024 k ----
    f32x4 acc0 = {0.f, 0.f, 0.f, 0.f}, acc1 = {0.f, 0.f, 0.f, 0.f};
    const f16x8* bb = (const f16x8*)&catw[wave][0];
#pragma unroll
    for (int i = 0; i < NT; i += 2) {
      f16x8 b0 = bb[i * 4 + q];
      f16x8 b1 = bb[(i + 1) * 4 + q];
      acc0 = __builtin_amdgcn_mfma_f32_16x16x32_f16(
          __builtin_bit_cast(f16x8, afrag[i]), b0, acc0, 0, 0, 0);
      acc1 = __builtin_amdgcn_mfma_f32_16x16x32_f16(
          __builtin_bit_cast(f16x8, afrag[i + 1]), b1, acc1, 0, 0, 0);
    }
    f32x4 accs = acc0 + acc1;
    // D layout: col=lane&15 (all equal), row=(lane>>4)*4+reg
    if (m == 0) *(f32x4*)&partials[t & 1][wave][q * 4] = accs;
    __syncthreads();   // the ONE barrier per step: partials ready for reduce

    // ---- waves 0 & 4: reduce 4 k-partials per row, relu, publish first ----
    if ((wave & 3) == 0 && lane < 16) {
      const int rbb = wave >> 2;
      const float* pp = &partials[t & 1][rbb * 4][0];
      float s = pp[0 * 16 + lane] + pp[1 * 16 + lane] +
                pp[2 * 16 + lane] + pp[3 * 16 + lane];
      s = fmaxf(s, 0.f);
      int gr = wg * ROWS_PER_WG + rbb * 16 + lane;
      unsigned int hb = (unsigned int)__builtin_bit_cast(unsigned short, (_Float16)s);
      unsigned int up = __shfl_down(hb, 1);          // odd row's bits
      if ((lane & 1) == 0) {
        unsigned int word = (hb & 0xFFFEu) | (unsigned int)(t & 1) | (up << 16);
        unsigned int* dst = (unsigned int*)&g_ring[layer][t][0] + (gr >> 1);
        __hip_atomic_store(dst, word, __ATOMIC_RELAXED, __HIP_MEMORY_SCOPE_AGENT);
      }
      if (layer == NL - 1) {
        out[(size_t)t * HID + gr] = s;                      // output[0, t, :]
        if (t == SEQ - 1) out[(size_t)SEQ * HID + gr] = s;  // h_last
      }
    }
    // no drain, no flag: the tagged store above is the publication.
  }
}

extern "C" void kernel_launch(void* const* d_in, const int* in_sizes, int n_in,
                              void* d_out, int out_size, void* d_ws, size_t ws_size,
                              hipStream_t stream) {
  const float* x   = (const float*)d_in[0];
  const float* wih = (const float*)d_in[1];
  const float* whh = (const float*)d_in[2];
  float* out = (float*)d_out;

  prep_kernel<<<8192, 1024, 0, stream>>>(x);
  rnn_kernel<<<NL * WGS_PER_LAYER, 512, 0, stream>>>(wih, whh, out);
}